// Round 3
// baseline (336.267 us; speedup 1.0000x reference)
//
#include <hip/hip_runtime.h>
#include <hip/hip_bf16.h>
#include <math.h>
#include <stdint.h>

// Problem constants
#define BATCH 8
#define SEQ   2048
#define DMODEL 1024
#define GROUPS 2
#define VOCAB 320
#define NOUT  (GROUPS*VOCAB)   // 640
#define DG    (DMODEL/GROUPS)  // 512
#define NTOK  (BATCH*SEQ)      // 16384
#define NPAIR (NTOK*GROUPS)    // 32768
#define NCHUNK 10              // 64-col chunks per token

#define MARGIN 4.0f
#define NEG_INF (-3.0e38f)

typedef __attribute__((ext_vector_type(8))) short short8;
typedef __attribute__((ext_vector_type(8))) unsigned short ushort8;
typedef __attribute__((ext_vector_type(4))) float f32x4;

__device__ __forceinline__ unsigned short f2bf(float f) {
    __hip_bfloat16 h = __float2bfloat16(f);   // RNE
    return *reinterpret_cast<unsigned short*>(&h);
}
__device__ __forceinline__ float bf2f(unsigned short u) {
    unsigned int x = ((unsigned int)u) << 16;
    return __uint_as_float(x);
}

// async global->LDS 16B copy (wave-uniform base + lane*16 on the LDS side)
__device__ __forceinline__ void async16(const void* gptr, const void* lptr) {
    __builtin_amdgcn_global_load_lds(
        (const __attribute__((address_space(1))) unsigned int*)(unsigned long long)(uintptr_t)gptr,
        (__attribute__((address_space(3))) unsigned int*)(unsigned int)(uintptr_t)lptr,
        16, 0, 0);
}

// ---------------------------------------------------------------------------
// Kernel 1: fp32 -> bf16 conversion of X and W; block 0 also zeroes the
// per-iteration scratch scalars (nAmb, done, hist) so no memset node needed.
// ---------------------------------------------------------------------------
#define NX4 (NTOK*DMODEL/4)    // 4194304
#define NW4 (NOUT*DMODEL/4)    // 163840
__global__ __launch_bounds__(256) void convert_kernel(
    const float* __restrict__ X, const float* __restrict__ W,
    unsigned short* __restrict__ Xb, unsigned short* __restrict__ Wb,
    int* __restrict__ nAmb, int* __restrict__ done, int* __restrict__ hist)
{
    int i = blockIdx.x * 256 + threadIdx.x;
    if (blockIdx.x == 0) {
        for (int k = threadIdx.x; k < NOUT; k += 256) hist[k] = 0;
        if (threadIdx.x == 0) { *nAmb = 0; *done = 0; }
    }
    const float4* src;
    ushort4* dst;
    int j;
    if (i < NX4) { src = (const float4*)X; dst = (ushort4*)Xb; j = i; }
    else         { src = (const float4*)W; dst = (ushort4*)Wb; j = i - NX4; if (j >= NW4) return; }
    float4 v = src[j];
    ushort4 u;
    u.x = f2bf(v.x); u.y = f2bf(v.y); u.z = f2bf(v.z); u.w = f2bf(v.w);
    dst[j] = u;
}

// ---------------------------------------------------------------------------
// Kernel 2: bf16 MFMA GEMM + fused per-(token,chunk) (max1,max2,argmax).
// PROVEN round-1 single-buffered structure (STAGE -> sync -> MFMA -> sync);
// tile changed 128x128 -> 128x64 so grid = 1280 blocks (5/CU) to fix the
// occupancy starvation (was 640 blocks, 2.5/CU, MfmaUtil 18%).
// Wave layout 4Mx1N: each wave 32 rows x 64 cols (acc[2][4]); the 64-col
// wave tile == one chunk, so the 16-lane epilogue reduction is unchanged.
// ---------------------------------------------------------------------------
__global__ __launch_bounds__(256) void gemm_bf16_kernel(
    const unsigned short* __restrict__ Xb,   // [16384][1024]
    const unsigned short* __restrict__ Wb,   // [640][1024]
    const float* __restrict__ bias,          // [640]
    unsigned short* __restrict__ logits,     // [16384][640] bf16
    float* __restrict__ rec_m1,              // [NTOK][NCHUNK]
    float* __restrict__ rec_m2,              // [NTOK][NCHUNK]
    int*   __restrict__ rec_id)              // [NTOK][NCHUNK] (global col)
{
    __shared__ __align__(16) unsigned short As[128 * 32];  // 8 KB
    __shared__ __align__(16) unsigned short Bs[64 * 32];   // 4 KB

    const int tid  = threadIdx.x;
    const int lane = tid & 63;
    const int wave = tid >> 6;
    const int m0 = blockIdx.x * 128;
    const int n0 = blockIdx.y * 64;
    const int wm = wave * 32;

    f32x4 acc[2][4];
    #pragma unroll
    for (int a = 0; a < 2; a++)
        #pragma unroll
        for (int b = 0; b < 4; b++)
            acc[a][b] = (f32x4)0.0f;

    int aoff[2], loffA[2], boff, loffB;
    #pragma unroll
    for (int j = 0; j < 2; j++) {
        int p = tid + j * 256;
        int r = p >> 2, s = p & 3;
        int c = s ^ ((r >> 1) & 3);
        aoff[j] = (m0 + r) * DMODEL + c * 8;
        loffA[j] = p * 8;
    }
    {
        int p = tid;
        int r = p >> 2, s = p & 3;
        int c = s ^ ((r >> 1) & 3);
        boff = (n0 + r) * DMODEL + c * 8;
        loffB = p * 8;
    }

    int afrag[2], bfrag[4];
    {
        int rho = lane & 15, h = lane >> 4;
        #pragma unroll
        for (int mi = 0; mi < 2; mi++) {
            int r = wm + mi * 16 + rho;
            afrag[mi] = (4 * r + (h ^ ((r >> 1) & 3))) * 8;
        }
        #pragma unroll
        for (int ni = 0; ni < 4; ni++) {
            int rn = ni * 16 + rho;
            bfrag[ni] = (4 * rn + (h ^ ((rn >> 1) & 3))) * 8;
        }
    }

    for (int k0 = 0; k0 < DMODEL; k0 += 32) {
        async16(Xb + aoff[0] + k0, As + loffA[0]);
        async16(Xb + aoff[1] + k0, As + loffA[1]);
        async16(Wb + boff + k0, Bs + loffB);
        __syncthreads();

        short8 af[2], bf[4];
        #pragma unroll
        for (int mi = 0; mi < 2; mi++) af[mi] = *(const short8*)&As[afrag[mi]];
        #pragma unroll
        for (int ni = 0; ni < 4; ni++) bf[ni] = *(const short8*)&Bs[bfrag[ni]];
        #pragma unroll
        for (int mi = 0; mi < 2; mi++)
            #pragma unroll
            for (int ni = 0; ni < 4; ni++)
                acc[mi][ni] = __builtin_amdgcn_mfma_f32_16x16x32_bf16(
                    af[mi], bf[ni], acc[mi][ni], 0, 0, 0);
        __syncthreads();
    }

    // Epilogue: bias add, bf16 logit store, per-row (64-col) max1/max2/idx
    const int colb = n0 + (lane & 15);
    const int rowb = m0 + wm + (lane >> 4) * 4;
    const int chunk = blockIdx.y;       // 0..9
    float bv[4];
    #pragma unroll
    for (int ni = 0; ni < 4; ni++) bv[ni] = bias[colb + ni * 16];

    #pragma unroll
    for (int mi = 0; mi < 2; mi++) {
        #pragma unroll
        for (int p = 0; p < 4; p++) {
            const int row = rowb + mi * 16 + p;
            // local max over this lane's 4 cols (ascending col order)
            float m1 = acc[mi][0][p] + bv[0];
            float m2 = NEG_INF;
            int i1 = colb;
            logits[row * NOUT + colb] = f2bf(m1);
            #pragma unroll
            for (int ni = 1; ni < 4; ni++) {
                float v = acc[mi][ni][p] + bv[ni];
                logits[row * NOUT + colb + ni * 16] = f2bf(v);
                if (v > m1) { m2 = m1; m1 = v; i1 = colb + ni * 16; }
                else        { m2 = fmaxf(m2, v); }
            }
            // reduce across the 16 lanes of this row group (xor 1,2,4,8)
            #pragma unroll
            for (int off = 1; off < 16; off <<= 1) {
                float om1 = __shfl_xor(m1, off);
                float om2 = __shfl_xor(m2, off);
                int   oi  = __shfl_xor(i1, off);
                float nm2 = fmaxf(fmaxf(m2, om2), fminf(m1, om1));
                if (om1 > m1 || (om1 == m1 && oi < i1)) { m1 = om1; i1 = oi; }
                m2 = nm2;
            }
            if ((lane & 15) == 0) {
                rec_m1[row * NCHUNK + chunk] = m1;
                rec_m2[row * NCHUNK + chunk] = m2;
                rec_id[row * NCHUNK + chunk] = i1;
            }
        }
    }
}

// ---------------------------------------------------------------------------
// Kernel 3: dense reduce, thread-per-pair. Unique -> idx; ambiguous ->
// append (M, pair) to list via wave-aggregated atomic.
// ---------------------------------------------------------------------------
__global__ __launch_bounds__(256) void reduce_kernel(
    const float* __restrict__ rec_m1, const float* __restrict__ rec_m2,
    const int* __restrict__ rec_id,
    float* __restrict__ out_idx,
    unsigned long long* __restrict__ list, int* __restrict__ nAmb)
{
    const int pair = blockIdx.x * 256 + threadIdx.x;   // 32768 threads
    const int token = pair >> 1;
    const int g = pair & 1;
    const int base = token * NCHUNK + g * 5;

    float m1[5], m2s, M;
    int cstar = 0;
    #pragma unroll
    for (int c = 0; c < 5; c++) m1[c] = rec_m1[base + c];
    M = m1[0];
    #pragma unroll
    for (int c = 1; c < 5; c++)
        if (m1[c] > M) { M = m1[c]; cstar = c; }
    m2s = rec_m2[base + cstar];

    const float thr = M - MARGIN;
    bool amb = (m2s >= thr);
    #pragma unroll
    for (int c = 0; c < 5; c++)
        if (c != cstar && m1[c] >= thr) amb = true;

    if (!amb) {
        out_idx[pair] = (float)(rec_id[base + cstar] - g * VOCAB);
    } else {
        out_idx[pair] = -1.0f;
    }

    // wave-aggregated append
    unsigned long long mask = __ballot(amb);
    if (mask) {
        const int lane = threadIdx.x & 63;
        const int leader = __ffsll((long long)mask) - 1;
        int basepos = 0;
        if (lane == leader) basepos = atomicAdd(nAmb, (int)__popcll(mask));
        basepos = __shfl(basepos, leader);
        if (amb) {
            int off = __popcll(mask & ((1ull << lane) - 1ull));
            list[basepos + off] =
                ((unsigned long long)__float_as_uint(M) << 32) | (unsigned int)pair;
        }
    }
}

// ---------------------------------------------------------------------------
// Kernel 4: FUSED extract+rescore — wave-per-slot (grid-stride over slots).
// The wave scans the pair's bf16 logit row, ballot-finds candidates >= M-MARGIN,
// and immediately rescores each with an exact fp32 dot (X row cached in regs,
// W row L2-resident, butterfly reduce). Dot order identical to the proven
// round-1 rescore. No cand/cnt round-trip, no candidate-count cap.
// ---------------------------------------------------------------------------
__global__ __launch_bounds__(256) void resolve_kernel(
    const float* __restrict__ X, const float* __restrict__ W,
    const float* __restrict__ bias,
    const unsigned short* __restrict__ logits,
    const unsigned long long* __restrict__ list, const int* __restrict__ nAmb,
    float* __restrict__ out_idx)
{
    const int lane  = threadIdx.x & 63;
    const int wglob = (blockIdx.x * 256 + threadIdx.x) >> 6;  // global wave id
    const int nwav  = gridDim.x * 4;                          // waves in grid
    const int n     = *nAmb;

    for (int slot = wglob; slot < n; slot += nwav) {
        const unsigned long long e = list[slot];
        const int pair  = (int)(e & 0xFFFFFFFFull);
        const float M   = __uint_as_float((unsigned int)(e >> 32));
        const int token = pair >> 1;
        const int g     = pair & 1;

        // cache this token's X row: 16 floats per lane
        const float4* xr = (const float4*)(X + (size_t)token * DMODEL);
        float4 xv[4];
        #pragma unroll
        for (int q = 0; q < 4; q++) xv[q] = xr[lane + 64 * q];

        // load this pair's bf16 logit row (40 lanes x 8 values = 320)
        const unsigned short* lp = logits + token * NOUT + g * VOCAB;
        const bool have = (lane < 40);
        ushort8 u = (ushort8)0;
        if (have) u = *(const ushort8*)(lp + lane * 8);

        const float thr = M - MARGIN;
        float best = NEG_INF;
        int bestcol = 0;

        #pragma unroll
        for (int j = 0; j < 8; j++) {
            bool c = have && (bf2f(u[j]) >= thr);
            unsigned long long mask = __ballot(c);   // wave-uniform
            while (mask) {
                const int b = __ffsll((long long)mask) - 1;
                mask &= mask - 1;
                const int col = b * 8 + j;           // 0..319
                const float4* wr = (const float4*)(W + (size_t)(g * VOCAB + col) * DMODEL);
                float acc = 0.0f;
                #pragma unroll
                for (int q = 0; q < 4; q++) {
                    float4 bb = wr[lane + 64 * q];
                    acc = fmaf(xv[q].x, bb.x, acc);
                    acc = fmaf(xv[q].y, bb.y, acc);
                    acc = fmaf(xv[q].z, bb.z, acc);
                    acc = fmaf(xv[q].w, bb.w, acc);
                }
                #pragma unroll
                for (int off = 32; off >= 1; off >>= 1)
                    acc += __shfl_xor(acc, off);
                const float logit = acc + bias[g * VOCAB + col];
                if (logit > best || (logit == best && col < bestcol)) {
                    best = logit; bestcol = col;
                }
            }
        }
        if (lane == 0) out_idx[pair] = (float)bestcol;
    }
}

// ---------------------------------------------------------------------------
// Kernel 5: block-cooperative finalize + gather (16 tokens / block),
// with the diversity-loss computation fused into the LAST finishing block
// (threadfence + done counter; hist read back via atomicAdd(p,0) for
// device-scope coherence).
// ---------------------------------------------------------------------------
__global__ __launch_bounds__(256) void gather_kernel(
    const float* __restrict__ cb,
    const float* __restrict__ out_idx,
    float* __restrict__ out,
    int* __restrict__ hist, int* __restrict__ done,
    float* __restrict__ out_loss)
{
    __shared__ int gidx[32];
    __shared__ int lastFlag;
    __shared__ float s0[256], s1[256];
    const int t0 = blockIdx.x * 16;     // first token
    const int tid = threadIdx.x;

    if (tid < 32) {
        const int pair = t0 * 2 + tid;
        const int g = pair & 1;
        const int col = (int)out_idx[pair];
        gidx[tid] = g * VOCAB + col;
        atomicAdd(&hist[g * VOCAB + col], 1);
    }
    __syncthreads();

    // copy 16 tokens x 1024 floats; per iter: 256 float4 = one token row
    #pragma unroll 4
    for (int i = 0; i < 16; i++) {
        const int token = t0 + i;
        const int gg = tid >> 7;
        const float4* src = (const float4*)(cb + (size_t)gidx[i * 2 + gg] * DG);
        ((float4*)(out + (size_t)token * DMODEL))[tid] = src[tid & 127];
    }

    // --- fused diversity loss: last block to finish computes it ---
    __threadfence();
    if (tid == 0) lastFlag = (atomicAdd(done, 1) == (int)gridDim.x - 1);
    __syncthreads();
    if (!lastFlag) return;

    float a0 = 0.0f, a1 = 0.0f;
    for (int i = tid; i < NOUT; i += 256) {
        int h = atomicAdd(&hist[i], 0);      // coherent readback
        float m = (float)h * (1.0f / (float)NTOK);
        float t = m * logf(m + 1e-7f);
        if (i < VOCAB) a0 += t; else a1 += t;
    }
    s0[tid] = a0; s1[tid] = a1;
    __syncthreads();
    for (int s = 128; s > 0; s >>= 1) {
        if (tid < s) { s0[tid] += s0[tid + s]; s1[tid] += s1[tid + s]; }
        __syncthreads();
    }
    if (tid == 0) {
        float perplexity = expf(-s0[0]) + expf(-s1[0]);
        *out_loss = ((float)NOUT - perplexity) / (float)NOUT * 0.1f;
    }
}

// ---------------------------------------------------------------------------
extern "C" void kernel_launch(void* const* d_in, const int* in_sizes, int n_in,
                              void* d_out, int out_size, void* d_ws, size_t ws_size,
                              hipStream_t stream) {
    const float* X    = (const float*)d_in[0];
    const float* W    = (const float*)d_in[1];
    const float* bias = (const float*)d_in[2];
    const float* cb   = (const float*)d_in[3];

    float* out      = (float*)d_out;
    float* out_idx  = out + (size_t)NTOK * DMODEL;
    float* out_loss = out_idx + NPAIR;

    // workspace layout
    char* p = (char*)d_ws;
    unsigned short* Xb = (unsigned short*)p;      p += (size_t)NTOK * DMODEL * 2;   // 32 MB
    unsigned short* Wb = (unsigned short*)p;      p += (size_t)NOUT * DMODEL * 2;   // 1.25 MB
    unsigned short* logits = (unsigned short*)p;  p += (size_t)NTOK * NOUT * 2;     // 20 MB
    float* rec_m1 = (float*)p;                    p += (size_t)NTOK * NCHUNK * 4;   // 640 KB
    float* rec_m2 = (float*)p;                    p += (size_t)NTOK * NCHUNK * 4;
    int*   rec_id = (int*)p;                      p += (size_t)NTOK * NCHUNK * 4;
    unsigned long long* list = (unsigned long long*)p; p += (size_t)NPAIR * 8;      // 256 KB
    int* nAmb = (int*)p;                          p += 256;
    int* done = (int*)p;                          p += 256;
    int* hist = (int*)p;                          p += NOUT * 4;

    convert_kernel<<<(NX4 + NW4) / 256, 256, 0, stream>>>(X, W, Xb, Wb,
                                                          nAmb, done, hist);

    dim3 ggrid(NTOK / 128, NOUT / 64);  // 128 x 10 = 1280 blocks
    gemm_bf16_kernel<<<ggrid, 256, 0, stream>>>(Xb, Wb, bias, logits,
                                                rec_m1, rec_m2, rec_id);

    reduce_kernel<<<NPAIR / 256, 256, 0, stream>>>(rec_m1, rec_m2, rec_id,
                                                   out_idx, list, nAmb);

    // 2048 blocks x 4 waves = 8192 waves; grid-stride over nAmb slots
    resolve_kernel<<<2048, 256, 0, stream>>>(X, W, bias, logits, list, nAmb,
                                             out_idx);

    gather_kernel<<<NTOK / 16, 256, 0, stream>>>(cb, out_idx, out,
                                                 hist, done, out_loss);
}

// Round 4
// 209.692 us; speedup vs baseline: 1.6036x; 1.6036x over previous
//
#include <hip/hip_runtime.h>
#include <hip/hip_bf16.h>
#include <math.h>
#include <stdint.h>

// Problem constants
#define BATCH 8
#define SEQ   2048
#define DMODEL 1024
#define GROUPS 2
#define VOCAB 320
#define NOUT  (GROUPS*VOCAB)   // 640
#define DG    (DMODEL/GROUPS)  // 512
#define NTOK  (BATCH*SEQ)      // 16384
#define NPAIR (NTOK*GROUPS)    // 32768
#define NCHUNK 10              // 64-col chunks per token

#define MARGIN 4.0f
#define NEG_INF (-3.0e38f)

typedef __attribute__((ext_vector_type(8))) short short8;
typedef __attribute__((ext_vector_type(8))) unsigned short ushort8;
typedef __attribute__((ext_vector_type(4))) float f32x4;

__device__ __forceinline__ unsigned short f2bf(float f) {
    __hip_bfloat16 h = __float2bfloat16(f);   // RNE
    return *reinterpret_cast<unsigned short*>(&h);
}
__device__ __forceinline__ float bf2f(unsigned short u) {
    unsigned int x = ((unsigned int)u) << 16;
    return __uint_as_float(x);
}

// async global->LDS 16B copy (wave-uniform base + lane*16 on the LDS side)
__device__ __forceinline__ void async16(const void* gptr, const void* lptr) {
    __builtin_amdgcn_global_load_lds(
        (const __attribute__((address_space(1))) unsigned int*)(unsigned long long)(uintptr_t)gptr,
        (__attribute__((address_space(3))) unsigned int*)(unsigned int)(uintptr_t)lptr,
        16, 0, 0);
}

// ---------------------------------------------------------------------------
// Kernel 1: fp32 -> bf16 conversion of X and W; block 0 zeroes nAmb.
// ---------------------------------------------------------------------------
#define NX4 (NTOK*DMODEL/4)    // 4194304
#define NW4 (NOUT*DMODEL/4)    // 163840
__global__ __launch_bounds__(256) void convert_kernel(
    const float* __restrict__ X, const float* __restrict__ W,
    unsigned short* __restrict__ Xb, unsigned short* __restrict__ Wb,
    int* __restrict__ nAmb)
{
    int i = blockIdx.x * 256 + threadIdx.x;
    if (i == 0) *nAmb = 0;
    const float4* src;
    ushort4* dst;
    int j;
    if (i < NX4) { src = (const float4*)X; dst = (ushort4*)Xb; j = i; }
    else         { src = (const float4*)W; dst = (ushort4*)Wb; j = i - NX4; if (j >= NW4) return; }
    float4 v = src[j];
    ushort4 u;
    u.x = f2bf(v.x); u.y = f2bf(v.y); u.z = f2bf(v.z); u.w = f2bf(v.w);
    dst[j] = u;
}

// ---------------------------------------------------------------------------
// Kernel 2: bf16 MFMA GEMM + fused per-(token,chunk) (max1,max2,argmax).
// Single-buffered proven structure; 128x64 tile -> 1280 blocks (5/CU).
// Wave layout 4Mx1N: each wave 32 rows x 64 cols (acc[2][4]); the 64-col
// wave tile == one chunk, so the 16-lane epilogue reduction is unchanged.
// ---------------------------------------------------------------------------
__global__ __launch_bounds__(256) void gemm_bf16_kernel(
    const unsigned short* __restrict__ Xb,   // [16384][1024]
    const unsigned short* __restrict__ Wb,   // [640][1024]
    const float* __restrict__ bias,          // [640]
    unsigned short* __restrict__ logits,     // [16384][640] bf16
    float* __restrict__ rec_m1,              // [NTOK][NCHUNK]
    float* __restrict__ rec_m2,              // [NTOK][NCHUNK]
    int*   __restrict__ rec_id)              // [NTOK][NCHUNK] (global col)
{
    __shared__ __align__(16) unsigned short As[128 * 32];  // 8 KB
    __shared__ __align__(16) unsigned short Bs[64 * 32];   // 4 KB

    const int tid  = threadIdx.x;
    const int lane = tid & 63;
    const int wave = tid >> 6;
    const int m0 = blockIdx.x * 128;
    const int n0 = blockIdx.y * 64;
    const int wm = wave * 32;

    f32x4 acc[2][4];
    #pragma unroll
    for (int a = 0; a < 2; a++)
        #pragma unroll
        for (int b = 0; b < 4; b++)
            acc[a][b] = (f32x4)0.0f;

    int aoff[2], loffA[2], boff, loffB;
    #pragma unroll
    for (int j = 0; j < 2; j++) {
        int p = tid + j * 256;
        int r = p >> 2, s = p & 3;
        int c = s ^ ((r >> 1) & 3);
        aoff[j] = (m0 + r) * DMODEL + c * 8;
        loffA[j] = p * 8;
    }
    {
        int p = tid;
        int r = p >> 2, s = p & 3;
        int c = s ^ ((r >> 1) & 3);
        boff = (n0 + r) * DMODEL + c * 8;
        loffB = p * 8;
    }

    int afrag[2], bfrag[4];
    {
        int rho = lane & 15, h = lane >> 4;
        #pragma unroll
        for (int mi = 0; mi < 2; mi++) {
            int r = wm + mi * 16 + rho;
            afrag[mi] = (4 * r + (h ^ ((r >> 1) & 3))) * 8;
        }
        #pragma unroll
        for (int ni = 0; ni < 4; ni++) {
            int rn = ni * 16 + rho;
            bfrag[ni] = (4 * rn + (h ^ ((rn >> 1) & 3))) * 8;
        }
    }

    for (int k0 = 0; k0 < DMODEL; k0 += 32) {
        async16(Xb + aoff[0] + k0, As + loffA[0]);
        async16(Xb + aoff[1] + k0, As + loffA[1]);
        async16(Wb + boff + k0, Bs + loffB);
        __syncthreads();

        short8 af[2], bf[4];
        #pragma unroll
        for (int mi = 0; mi < 2; mi++) af[mi] = *(const short8*)&As[afrag[mi]];
        #pragma unroll
        for (int ni = 0; ni < 4; ni++) bf[ni] = *(const short8*)&Bs[bfrag[ni]];
        #pragma unroll
        for (int mi = 0; mi < 2; mi++)
            #pragma unroll
            for (int ni = 0; ni < 4; ni++)
                acc[mi][ni] = __builtin_amdgcn_mfma_f32_16x16x32_bf16(
                    af[mi], bf[ni], acc[mi][ni], 0, 0, 0);
        __syncthreads();
    }

    // Epilogue: bias add, bf16 logit store, per-row (64-col) max1/max2/idx
    const int colb = n0 + (lane & 15);
    const int rowb = m0 + wm + (lane >> 4) * 4;
    const int chunk = blockIdx.y;       // 0..9
    float bv[4];
    #pragma unroll
    for (int ni = 0; ni < 4; ni++) bv[ni] = bias[colb + ni * 16];

    #pragma unroll
    for (int mi = 0; mi < 2; mi++) {
        #pragma unroll
        for (int p = 0; p < 4; p++) {
            const int row = rowb + mi * 16 + p;
            // local max over this lane's 4 cols (ascending col order)
            float m1 = acc[mi][0][p] + bv[0];
            float m2 = NEG_INF;
            int i1 = colb;
            logits[row * NOUT + colb] = f2bf(m1);
            #pragma unroll
            for (int ni = 1; ni < 4; ni++) {
                float v = acc[mi][ni][p] + bv[ni];
                logits[row * NOUT + colb + ni * 16] = f2bf(v);
                if (v > m1) { m2 = m1; m1 = v; i1 = colb + ni * 16; }
                else        { m2 = fmaxf(m2, v); }
            }
            // reduce across the 16 lanes of this row group (xor 1,2,4,8)
            #pragma unroll
            for (int off = 1; off < 16; off <<= 1) {
                float om1 = __shfl_xor(m1, off);
                float om2 = __shfl_xor(m2, off);
                int   oi  = __shfl_xor(i1, off);
                float nm2 = fmaxf(fmaxf(m2, om2), fminf(m1, om1));
                if (om1 > m1 || (om1 == m1 && oi < i1)) { m1 = om1; i1 = oi; }
                m2 = nm2;
            }
            if ((lane & 15) == 0) {
                rec_m1[row * NCHUNK + chunk] = m1;
                rec_m2[row * NCHUNK + chunk] = m2;
                rec_id[row * NCHUNK + chunk] = i1;
            }
        }
    }
}

// ---------------------------------------------------------------------------
// Kernel 3: dense reduce, thread-per-pair. Unique -> idx; ambiguous ->
// append (M, pair) to list via wave-aggregated atomic.
// ---------------------------------------------------------------------------
__global__ __launch_bounds__(256) void reduce_kernel(
    const float* __restrict__ rec_m1, const float* __restrict__ rec_m2,
    const int* __restrict__ rec_id,
    float* __restrict__ out_idx,
    unsigned long long* __restrict__ list, int* __restrict__ nAmb)
{
    const int pair = blockIdx.x * 256 + threadIdx.x;   // 32768 threads
    const int token = pair >> 1;
    const int g = pair & 1;
    const int base = token * NCHUNK + g * 5;

    float m1[5], m2s, M;
    int cstar = 0;
    #pragma unroll
    for (int c = 0; c < 5; c++) m1[c] = rec_m1[base + c];
    M = m1[0];
    #pragma unroll
    for (int c = 1; c < 5; c++)
        if (m1[c] > M) { M = m1[c]; cstar = c; }
    m2s = rec_m2[base + cstar];

    const float thr = M - MARGIN;
    bool amb = (m2s >= thr);
    #pragma unroll
    for (int c = 0; c < 5; c++)
        if (c != cstar && m1[c] >= thr) amb = true;

    if (!amb) {
        out_idx[pair] = (float)(rec_id[base + cstar] - g * VOCAB);
    } else {
        out_idx[pair] = -1.0f;
    }

    // wave-aggregated append
    unsigned long long mask = __ballot(amb);
    if (mask) {
        const int lane = threadIdx.x & 63;
        const int leader = __ffsll((long long)mask) - 1;
        int basepos = 0;
        if (lane == leader) basepos = atomicAdd(nAmb, (int)__popcll(mask));
        basepos = __shfl(basepos, leader);
        if (amb) {
            int off = __popcll(mask & ((1ull << lane) - 1ull));
            list[basepos + off] =
                ((unsigned long long)__float_as_uint(M) << 32) | (unsigned int)pair;
        }
    }
}

// ---------------------------------------------------------------------------
// Kernel 4: FUSED extract+rescore — wave-per-slot (grid-stride over slots).
// The wave scans the pair's bf16 logit row, ballot-finds candidates >= M-MARGIN,
// and immediately rescores each with an exact fp32 dot (X row cached in regs,
// W row L2-resident, butterfly reduce).
// ---------------------------------------------------------------------------
__global__ __launch_bounds__(256) void resolve_kernel(
    const float* __restrict__ X, const float* __restrict__ W,
    const float* __restrict__ bias,
    const unsigned short* __restrict__ logits,
    const unsigned long long* __restrict__ list, const int* __restrict__ nAmb,
    float* __restrict__ out_idx)
{
    const int lane  = threadIdx.x & 63;
    const int wglob = (blockIdx.x * 256 + threadIdx.x) >> 6;  // global wave id
    const int nwav  = gridDim.x * 4;                          // waves in grid
    const int n     = *nAmb;

    for (int slot = wglob; slot < n; slot += nwav) {
        const unsigned long long e = list[slot];
        const int pair  = (int)(e & 0xFFFFFFFFull);
        const float M   = __uint_as_float((unsigned int)(e >> 32));
        const int token = pair >> 1;
        const int g     = pair & 1;

        // cache this token's X row: 16 floats per lane
        const float4* xr = (const float4*)(X + (size_t)token * DMODEL);
        float4 xv[4];
        #pragma unroll
        for (int q = 0; q < 4; q++) xv[q] = xr[lane + 64 * q];

        // load this pair's bf16 logit row (40 lanes x 8 values = 320)
        const unsigned short* lp = logits + token * NOUT + g * VOCAB;
        const bool have = (lane < 40);
        ushort8 u = (ushort8)0;
        if (have) u = *(const ushort8*)(lp + lane * 8);

        const float thr = M - MARGIN;
        float best = NEG_INF;
        int bestcol = 0;

        #pragma unroll
        for (int j = 0; j < 8; j++) {
            bool c = have && (bf2f(u[j]) >= thr);
            unsigned long long mask = __ballot(c);   // wave-uniform
            while (mask) {
                const int b = __ffsll((long long)mask) - 1;
                mask &= mask - 1;
                const int col = b * 8 + j;           // 0..319
                const float4* wr = (const float4*)(W + (size_t)(g * VOCAB + col) * DMODEL);
                float acc = 0.0f;
                #pragma unroll
                for (int q = 0; q < 4; q++) {
                    float4 bb = wr[lane + 64 * q];
                    acc = fmaf(xv[q].x, bb.x, acc);
                    acc = fmaf(xv[q].y, bb.y, acc);
                    acc = fmaf(xv[q].z, bb.z, acc);
                    acc = fmaf(xv[q].w, bb.w, acc);
                }
                #pragma unroll
                for (int off = 32; off >= 1; off >>= 1)
                    acc += __shfl_xor(acc, off);
                const float logit = acc + bias[g * VOCAB + col];
                if (logit > best || (logit == best && col < bestcol)) {
                    best = logit; bestcol = col;
                }
            }
        }
        if (lane == 0) out_idx[pair] = (float)bestcol;
    }
}

// ---------------------------------------------------------------------------
// Kernel 5: pure block-cooperative gather (16 tokens / block).
// No atomics, no fences — just codebook row copies at write BW.
// ---------------------------------------------------------------------------
__global__ __launch_bounds__(256) void gather_kernel(
    const float* __restrict__ cb,
    const float* __restrict__ out_idx,
    float* __restrict__ out)
{
    __shared__ int gidx[32];
    const int t0 = blockIdx.x * 16;     // first token
    const int tid = threadIdx.x;

    if (tid < 32) {
        const int pair = t0 * 2 + tid;
        const int g = pair & 1;
        const int col = (int)out_idx[pair];
        gidx[tid] = g * VOCAB + col;
    }
    __syncthreads();

    // copy 16 tokens x 1024 floats; per iter: 256 float4 = one token row
    #pragma unroll 4
    for (int i = 0; i < 16; i++) {
        const int token = t0 + i;
        const int gg = tid >> 7;
        const float4* src = (const float4*)(cb + (size_t)gidx[i * 2 + gg] * DG);
        ((float4*)(out + (size_t)token * DMODEL))[tid] = src[tid & 127];
    }
}

// ---------------------------------------------------------------------------
// Kernel 6: diversity loss — single block builds the histogram from out_idx
// in LDS (LDS atomics) and computes the scalar. 128 KB read, trivial.
// ---------------------------------------------------------------------------
__global__ __launch_bounds__(256) void diversity_kernel(
    const float* __restrict__ out_idx, float* __restrict__ out_scalar)
{
    __shared__ int lhist[NOUT];
    __shared__ float s0[256], s1[256];
    const int tid = threadIdx.x;
    for (int i = tid; i < NOUT; i += 256) lhist[i] = 0;
    __syncthreads();

    // NPAIR = 32768 floats; read as float4 (pairs 4i..4i+3, g = pair&1)
    const float4* oi4 = (const float4*)out_idx;
    for (int i = tid; i < NPAIR / 4; i += 256) {
        float4 v = oi4[i];
        atomicAdd(&lhist[0 * VOCAB + (int)v.x], 1);   // pair 4i   : g=0
        atomicAdd(&lhist[1 * VOCAB + (int)v.y], 1);   // pair 4i+1 : g=1
        atomicAdd(&lhist[0 * VOCAB + (int)v.z], 1);   // pair 4i+2 : g=0
        atomicAdd(&lhist[1 * VOCAB + (int)v.w], 1);   // pair 4i+3 : g=1
    }
    __syncthreads();

    float a0 = 0.0f, a1 = 0.0f;
    for (int i = tid; i < NOUT; i += 256) {
        float m = (float)lhist[i] * (1.0f / (float)NTOK);
        float t = m * logf(m + 1e-7f);
        if (i < VOCAB) a0 += t; else a1 += t;
    }
    s0[tid] = a0; s1[tid] = a1;
    __syncthreads();
    for (int s = 128; s > 0; s >>= 1) {
        if (tid < s) { s0[tid] += s0[tid + s]; s1[tid] += s1[tid + s]; }
        __syncthreads();
    }
    if (tid == 0) {
        float perplexity = expf(-s0[0]) + expf(-s1[0]);
        *out_scalar = ((float)NOUT - perplexity) / (float)NOUT * 0.1f;
    }
}

// ---------------------------------------------------------------------------
extern "C" void kernel_launch(void* const* d_in, const int* in_sizes, int n_in,
                              void* d_out, int out_size, void* d_ws, size_t ws_size,
                              hipStream_t stream) {
    const float* X    = (const float*)d_in[0];
    const float* W    = (const float*)d_in[1];
    const float* bias = (const float*)d_in[2];
    const float* cb   = (const float*)d_in[3];

    float* out      = (float*)d_out;
    float* out_idx  = out + (size_t)NTOK * DMODEL;
    float* out_loss = out_idx + NPAIR;

    // workspace layout
    char* p = (char*)d_ws;
    unsigned short* Xb = (unsigned short*)p;      p += (size_t)NTOK * DMODEL * 2;   // 32 MB
    unsigned short* Wb = (unsigned short*)p;      p += (size_t)NOUT * DMODEL * 2;   // 1.25 MB
    unsigned short* logits = (unsigned short*)p;  p += (size_t)NTOK * NOUT * 2;     // 20 MB
    float* rec_m1 = (float*)p;                    p += (size_t)NTOK * NCHUNK * 4;   // 640 KB
    float* rec_m2 = (float*)p;                    p += (size_t)NTOK * NCHUNK * 4;
    int*   rec_id = (int*)p;                      p += (size_t)NTOK * NCHUNK * 4;
    unsigned long long* list = (unsigned long long*)p; p += (size_t)NPAIR * 8;      // 256 KB
    int* nAmb = (int*)p;                          p += 256;

    convert_kernel<<<(NX4 + NW4) / 256, 256, 0, stream>>>(X, W, Xb, Wb, nAmb);

    dim3 ggrid(NTOK / 128, NOUT / 64);  // 128 x 10 = 1280 blocks
    gemm_bf16_kernel<<<ggrid, 256, 0, stream>>>(Xb, Wb, bias, logits,
                                                rec_m1, rec_m2, rec_id);

    reduce_kernel<<<NPAIR / 256, 256, 0, stream>>>(rec_m1, rec_m2, rec_id,
                                                   out_idx, list, nAmb);

    // 2048 blocks x 4 waves = 8192 waves; grid-stride over nAmb slots
    resolve_kernel<<<2048, 256, 0, stream>>>(X, W, bias, logits, list, nAmb,
                                             out_idx);

    gather_kernel<<<NTOK / 16, 256, 0, stream>>>(cb, out_idx, out);

    diversity_kernel<<<1, 256, 0, stream>>>(out_idx, out_loss);
}

// Round 5
// 196.307 us; speedup vs baseline: 1.7130x; 1.0682x over previous
//
#include <hip/hip_runtime.h>
#include <hip/hip_bf16.h>
#include <math.h>
#include <stdint.h>

// Problem constants
#define BATCH 8
#define SEQ   2048
#define DMODEL 1024
#define GROUPS 2
#define VOCAB 320
#define NOUT  (GROUPS*VOCAB)   // 640
#define DG    (DMODEL/GROUPS)  // 512
#define NTOK  (BATCH*SEQ)      // 16384
#define NPAIR (NTOK*GROUPS)    // 32768
#define NCHUNK 10              // 64-col chunks per token

#define MARGIN 4.0f
#define NEG_INF (-3.0e38f)

typedef __attribute__((ext_vector_type(8))) short short8;
typedef __attribute__((ext_vector_type(8))) unsigned short ushort8;
typedef __attribute__((ext_vector_type(4))) float f32x4;

__device__ __forceinline__ unsigned short f2bf(float f) {
    __hip_bfloat16 h = __float2bfloat16(f);   // RNE
    return *reinterpret_cast<unsigned short*>(&h);
}
__device__ __forceinline__ float bf2f(unsigned short u) {
    unsigned int x = ((unsigned int)u) << 16;
    return __uint_as_float(x);
}

// async global->LDS 16B copy (wave-uniform base + lane*16 on the LDS side)
__device__ __forceinline__ void async16(const void* gptr, const void* lptr) {
    __builtin_amdgcn_global_load_lds(
        (const __attribute__((address_space(1))) unsigned int*)(unsigned long long)(uintptr_t)gptr,
        (__attribute__((address_space(3))) unsigned int*)(unsigned int)(uintptr_t)lptr,
        16, 0, 0);
}

// ---------------------------------------------------------------------------
// Kernel 1: fp32 -> bf16 conversion of X and W   (proven)
// ---------------------------------------------------------------------------
#define NX4 (NTOK*DMODEL/4)    // 4194304
#define NW4 (NOUT*DMODEL/4)    // 163840
__global__ __launch_bounds__(256) void convert_kernel(
    const float* __restrict__ X, const float* __restrict__ W,
    unsigned short* __restrict__ Xb, unsigned short* __restrict__ Wb)
{
    int i = blockIdx.x * 256 + threadIdx.x;
    const float4* src;
    ushort4* dst;
    int j;
    if (i < NX4) { src = (const float4*)X; dst = (ushort4*)Xb; j = i; }
    else         { src = (const float4*)W; dst = (ushort4*)Wb; j = i - NX4; if (j >= NW4) return; }
    float4 v = src[j];
    ushort4 u;
    u.x = f2bf(v.x); u.y = f2bf(v.y); u.z = f2bf(v.z); u.w = f2bf(v.w);
    dst[j] = u;
}

// ---------------------------------------------------------------------------
// Kernel 2: bf16 MFMA GEMM + fused per-(token,chunk) (max1,max2,argmax).
// PROVEN round-1 structure: 128x128 tile, single-buffered
// (STAGE -> sync -> MFMA -> sync), measured 45.4 us.
// (128x64 retile tried in r3/r4: 51 us, FETCH 22->38 MB — reverted.)
// ---------------------------------------------------------------------------
__global__ __launch_bounds__(256) void gemm_bf16_kernel(
    const unsigned short* __restrict__ Xb,   // [16384][1024]
    const unsigned short* __restrict__ Wb,   // [640][1024]
    const float* __restrict__ bias,          // [640]
    unsigned short* __restrict__ logits,     // [16384][640] bf16
    float* __restrict__ rec_m1,              // [NTOK][NCHUNK]
    float* __restrict__ rec_m2,              // [NTOK][NCHUNK]
    int*   __restrict__ rec_id)              // [NTOK][NCHUNK] (global col)
{
    __shared__ __align__(16) unsigned short As[128 * 32];  // 8 KB
    __shared__ __align__(16) unsigned short Bs[128 * 32];  // 8 KB

    const int tid  = threadIdx.x;
    const int lane = tid & 63;
    const int wave = tid >> 6;
    const int m0 = blockIdx.x * 128;
    const int n0 = blockIdx.y * 128;
    const int wm = (wave & 1) * 64;
    const int wn = (wave >> 1) * 64;

    f32x4 acc[4][4];
    #pragma unroll
    for (int a = 0; a < 4; a++)
        #pragma unroll
        for (int b = 0; b < 4; b++)
            acc[a][b] = (f32x4)0.0f;

    int aoff[2], boff[2], loff[2];
    #pragma unroll
    for (int j = 0; j < 2; j++) {
        int p = tid + j * 256;
        int r = p >> 2, s = p & 3;
        int c = s ^ ((r >> 1) & 3);
        aoff[j] = (m0 + r) * DMODEL + c * 8;
        boff[j] = (n0 + r) * DMODEL + c * 8;
        loff[j] = p * 8;
    }

    int afrag[4], bfrag[4];
    {
        int rho = lane & 15, h = lane >> 4;
        #pragma unroll
        for (int mi = 0; mi < 4; mi++) {
            int r = wm + mi * 16 + rho;
            afrag[mi] = (4 * r + (h ^ ((r >> 1) & 3))) * 8;
            int rn = wn + mi * 16 + rho;
            bfrag[mi] = (4 * rn + (h ^ ((rn >> 1) & 3))) * 8;
        }
    }

    for (int k0 = 0; k0 < DMODEL; k0 += 32) {
        #pragma unroll
        for (int j = 0; j < 2; j++) {
            async16(Xb + aoff[j] + k0, As + loff[j]);
            async16(Wb + boff[j] + k0, Bs + loff[j]);
        }
        __syncthreads();

        short8 af[4], bf[4];
        #pragma unroll
        for (int i = 0; i < 4; i++) {
            af[i] = *(const short8*)&As[afrag[i]];
            bf[i] = *(const short8*)&Bs[bfrag[i]];
        }
        #pragma unroll
        for (int mi = 0; mi < 4; mi++)
            #pragma unroll
            for (int ni = 0; ni < 4; ni++)
                acc[mi][ni] = __builtin_amdgcn_mfma_f32_16x16x32_bf16(
                    af[mi], bf[ni], acc[mi][ni], 0, 0, 0);
        __syncthreads();
    }

    // Epilogue: bias add, bf16 logit store, per-row (64-col) max1/max2/idx
    const int colb = n0 + wn + (lane & 15);
    const int rowb = m0 + wm + (lane >> 4) * 4;
    const int chunk = (n0 + wn) >> 6;   // 0..9
    float bv[4];
    #pragma unroll
    for (int ni = 0; ni < 4; ni++) bv[ni] = bias[colb + ni * 16];

    #pragma unroll
    for (int mi = 0; mi < 4; mi++) {
        #pragma unroll
        for (int p = 0; p < 4; p++) {
            const int row = rowb + mi * 16 + p;
            // local max over this lane's 4 cols (ascending col order)
            float m1 = acc[mi][0][p] + bv[0];
            float m2 = NEG_INF;
            int i1 = colb;
            logits[row * NOUT + colb] = f2bf(m1);
            #pragma unroll
            for (int ni = 1; ni < 4; ni++) {
                float v = acc[mi][ni][p] + bv[ni];
                logits[row * NOUT + colb + ni * 16] = f2bf(v);
                if (v > m1) { m2 = m1; m1 = v; i1 = colb + ni * 16; }
                else        { m2 = fmaxf(m2, v); }
            }
            // reduce across the 16 lanes of this row group (xor 1,2,4,8)
            #pragma unroll
            for (int off = 1; off < 16; off <<= 1) {
                float om1 = __shfl_xor(m1, off);
                float om2 = __shfl_xor(m2, off);
                int   oi  = __shfl_xor(i1, off);
                float nm2 = fmaxf(fmaxf(m2, om2), fminf(m1, om1));
                if (om1 > m1 || (om1 == m1 && oi < i1)) { m1 = om1; i1 = oi; }
                m2 = nm2;
            }
            if ((lane & 15) == 0) {
                rec_m1[row * NCHUNK + chunk] = m1;
                rec_m2[row * NCHUNK + chunk] = m2;
                rec_id[row * NCHUNK + chunk] = i1;
            }
        }
    }
}

// ---------------------------------------------------------------------------
// Kernel 3: FUSED reduce + resolve + gather. 512 blocks; block b owns
// pairs [b*64, b*64+64) == tokens [b*32, b*32+32). All block-local:
//   phase 1 (wave 0): per-pair chunk reduce; ambiguous -> LDS list (ballot)
//   phase 2 (4 waves): wave-per-slot bf16 scan + exact fp32 rescore
//   phase 3 (256 thr): gather the 32 token rows from the codebook
// No global list / nAmb / atomics; kills 2 dispatch nodes + round-trips.
// ---------------------------------------------------------------------------
__global__ __launch_bounds__(256) void finalize_kernel(
    const float* __restrict__ X, const float* __restrict__ W,
    const float* __restrict__ bias,
    const unsigned short* __restrict__ logits,
    const float* __restrict__ rec_m1, const float* __restrict__ rec_m2,
    const int* __restrict__ rec_id,
    const float* __restrict__ cb,
    float* __restrict__ out, float* __restrict__ out_idx)
{
    __shared__ int   lcol[64];    // global codebook row per local pair
    __shared__ float lM[64];      // chunk-max for ambiguous pairs
    __shared__ int   lamb[64];    // compacted local indices of ambiguous pairs
    __shared__ int   slcnt;

    const int tid   = threadIdx.x;
    const int lane  = tid & 63;
    const int wave  = tid >> 6;
    const int pair0 = blockIdx.x * 64;

    // ---- phase 1: reduce (wave 0 only; lane == local pair index) ----
    if (tid < 64) {
        const int pair  = pair0 + tid;
        const int token = pair >> 1;
        const int g     = pair & 1;
        const int base  = token * NCHUNK + g * 5;

        float m1[5], M;
        int cstar = 0;
        #pragma unroll
        for (int c = 0; c < 5; c++) m1[c] = rec_m1[base + c];
        M = m1[0];
        #pragma unroll
        for (int c = 1; c < 5; c++)
            if (m1[c] > M) { M = m1[c]; cstar = c; }
        const float m2s = rec_m2[base + cstar];

        const float thr = M - MARGIN;
        bool amb = (m2s >= thr);
        #pragma unroll
        for (int c = 0; c < 5; c++)
            if (c != cstar && m1[c] >= thr) amb = true;

        if (!amb) {
            const int gcol = rec_id[base + cstar];       // global col
            lcol[tid] = gcol;
            out_idx[pair] = (float)(gcol - g * VOCAB);
        } else {
            lM[tid] = M;
        }
        unsigned long long mask = __ballot(amb);
        if (amb) {
            int off = __popcll(mask & ((1ull << tid) - 1ull));
            lamb[off] = tid;
        }
        if (tid == 0) slcnt = (int)__popcll(mask);
    }
    __syncthreads();
    const int nloc = slcnt;

    // ---- phase 2: resolve ambiguous (wave-per-slot over LDS list) ----
    for (int s = wave; s < nloc; s += 4) {
        const int lp    = lamb[s];
        const int pair  = pair0 + lp;
        const float M   = lM[lp];
        const int token = pair >> 1;
        const int g     = pair & 1;

        // cache this token's X row: 16 floats per lane
        const float4* xr = (const float4*)(X + (size_t)token * DMODEL);
        float4 xv[4];
        #pragma unroll
        for (int q = 0; q < 4; q++) xv[q] = xr[lane + 64 * q];

        // load this pair's bf16 logit row (40 lanes x 8 values = 320)
        const unsigned short* lp_ = logits + token * NOUT + g * VOCAB;
        const bool have = (lane < 40);
        ushort8 u = (ushort8)0;
        if (have) u = *(const ushort8*)(lp_ + lane * 8);

        const float thr = M - MARGIN;
        float best = NEG_INF;
        int bestcol = 0;

        #pragma unroll
        for (int j = 0; j < 8; j++) {
            bool c = have && (bf2f(u[j]) >= thr);
            unsigned long long mask = __ballot(c);   // wave-uniform
            while (mask) {
                const int b = __ffsll((long long)mask) - 1;
                mask &= mask - 1;
                const int col = b * 8 + j;           // 0..319
                const float4* wr = (const float4*)(W + (size_t)(g * VOCAB + col) * DMODEL);
                float acc = 0.0f;
                #pragma unroll
                for (int q = 0; q < 4; q++) {
                    float4 bb = wr[lane + 64 * q];
                    acc = fmaf(xv[q].x, bb.x, acc);
                    acc = fmaf(xv[q].y, bb.y, acc);
                    acc = fmaf(xv[q].z, bb.z, acc);
                    acc = fmaf(xv[q].w, bb.w, acc);
                }
                #pragma unroll
                for (int off = 32; off >= 1; off >>= 1)
                    acc += __shfl_xor(acc, off);
                const float logit = acc + bias[g * VOCAB + col];
                if (logit > best || (logit == best && col < bestcol)) {
                    best = logit; bestcol = col;
                }
            }
        }
        if (lane == 0) {
            lcol[lp] = g * VOCAB + bestcol;
            out_idx[pair] = (float)bestcol;
        }
    }
    __syncthreads();

    // ---- phase 3: gather 32 tokens x 1024 floats (one row per iter) ----
    #pragma unroll 4
    for (int i = 0; i < 32; i++) {
        const int token = pair0 / 2 + i;
        const int gg = tid >> 7;
        const float4* src = (const float4*)(cb + (size_t)lcol[i * 2 + gg] * DG);
        ((float4*)(out + (size_t)token * DMODEL))[tid] = src[tid & 127];
    }
}

// ---------------------------------------------------------------------------
// Kernel 4: diversity loss — single block builds the histogram from out_idx
// in LDS (LDS atomics) and computes the scalar. 128 KB read, trivial.
// ---------------------------------------------------------------------------
__global__ __launch_bounds__(256) void diversity_kernel(
    const float* __restrict__ out_idx, float* __restrict__ out_scalar)
{
    __shared__ int lhist[NOUT];
    __shared__ float s0[256], s1[256];
    const int tid = threadIdx.x;
    for (int i = tid; i < NOUT; i += 256) lhist[i] = 0;
    __syncthreads();

    // NPAIR = 32768 floats; read as float4 (pairs 4i..4i+3, g = pair&1)
    const float4* oi4 = (const float4*)out_idx;
    for (int i = tid; i < NPAIR / 4; i += 256) {
        float4 v = oi4[i];
        atomicAdd(&lhist[0 * VOCAB + (int)v.x], 1);   // pair 4i   : g=0
        atomicAdd(&lhist[1 * VOCAB + (int)v.y], 1);   // pair 4i+1 : g=1
        atomicAdd(&lhist[0 * VOCAB + (int)v.z], 1);   // pair 4i+2 : g=0
        atomicAdd(&lhist[1 * VOCAB + (int)v.w], 1);   // pair 4i+3 : g=1
    }
    __syncthreads();

    float a0 = 0.0f, a1 = 0.0f;
    for (int i = tid; i < NOUT; i += 256) {
        float m = (float)lhist[i] * (1.0f / (float)NTOK);
        float t = m * logf(m + 1e-7f);
        if (i < VOCAB) a0 += t; else a1 += t;
    }
    s0[tid] = a0; s1[tid] = a1;
    __syncthreads();
    for (int s = 128; s > 0; s >>= 1) {
        if (tid < s) { s0[tid] += s0[tid + s]; s1[tid] += s1[tid + s]; }
        __syncthreads();
    }
    if (tid == 0) {
        float perplexity = expf(-s0[0]) + expf(-s1[0]);
        *out_scalar = ((float)NOUT - perplexity) / (float)NOUT * 0.1f;
    }
}

// ---------------------------------------------------------------------------
extern "C" void kernel_launch(void* const* d_in, const int* in_sizes, int n_in,
                              void* d_out, int out_size, void* d_ws, size_t ws_size,
                              hipStream_t stream) {
    const float* X    = (const float*)d_in[0];
    const float* W    = (const float*)d_in[1];
    const float* bias = (const float*)d_in[2];
    const float* cb   = (const float*)d_in[3];

    float* out      = (float*)d_out;
    float* out_idx  = out + (size_t)NTOK * DMODEL;
    float* out_loss = out_idx + NPAIR;

    // workspace layout
    char* p = (char*)d_ws;
    unsigned short* Xb = (unsigned short*)p;      p += (size_t)NTOK * DMODEL * 2;   // 32 MB
    unsigned short* Wb = (unsigned short*)p;      p += (size_t)NOUT * DMODEL * 2;   // 1.25 MB
    unsigned short* logits = (unsigned short*)p;  p += (size_t)NTOK * NOUT * 2;     // 20 MB
    float* rec_m1 = (float*)p;                    p += (size_t)NTOK * NCHUNK * 4;   // 640 KB
    float* rec_m2 = (float*)p;                    p += (size_t)NTOK * NCHUNK * 4;
    int*   rec_id = (int*)p;                      p += (size_t)NTOK * NCHUNK * 4;

    convert_kernel<<<(NX4 + NW4) / 256, 256, 0, stream>>>(X, W, Xb, Wb);

    dim3 ggrid(NTOK / 128, NOUT / 128);  // 128 x 5 = 640 blocks
    gemm_bf16_kernel<<<ggrid, 256, 0, stream>>>(Xb, Wb, bias, logits,
                                                rec_m1, rec_m2, rec_id);

    finalize_kernel<<<NPAIR / 64, 256, 0, stream>>>(X, W, bias, logits,
                                                    rec_m1, rec_m2, rec_id,
                                                    cb, out, out_idx);

    diversity_kernel<<<1, 256, 0, stream>>>(out_idx, out_loss);
}